// Round 1
// baseline (467.956 us; speedup 1.0000x reference)
//
#include <hip/hip_runtime.h>
#include <hip/hip_bf16.h>
#include <stdint.h>

#define N_ROWS 8192
#define DIM    1024
#define BM 256
#define BN 256
#define BKF 128          // fp8 bytes of K per tile (= one MFMA K)
#define NT (DIM / BKF)   // 8 K-tiles

typedef float   f32x4  __attribute__((ext_vector_type(4)));
typedef int     i32x4  __attribute__((ext_vector_type(4)));
typedef int     i32x8  __attribute__((ext_vector_type(8)));

// ---------------------------------------------------------------------------
// Kernel 1: fused L2-normalize (fp32 -> fp8 e4m3) + exact fp32 per-row
// diagonal + S zero-init (folds the memset dispatch).  UNCHANGED from R-best.
// ---------------------------------------------------------------------------
__global__ __launch_bounds__(256) void nrm_kernel(
    const float* __restrict__ img, const float* __restrict__ txt,
    uint8_t* __restrict__ img_f8, uint8_t* __restrict__ txt_f8,
    float* __restrict__ diag, float* __restrict__ S)
{
    const int row  = blockIdx.x;
    const int t    = threadIdx.x;
    const int lane = t & 63;
    const int w    = t >> 6;

    const float4 a = ((const float4*)(img + (size_t)row * DIM))[t];
    const float4 b = ((const float4*)(txt + (size_t)row * DIM))[t];

    float sa = a.x * a.x + a.y * a.y + a.z * a.z + a.w * a.w;
    float sb = b.x * b.x + b.y * b.y + b.z * b.z + b.w * b.w;
#pragma unroll
    for (int d = 1; d < 64; d <<= 1) {
        sa += __shfl_xor(sa, d, 64);
        sb += __shfl_xor(sb, d, 64);
    }
    __shared__ float red[3][4];
    if (lane == 0) { red[0][w] = sa; red[1][w] = sb; }
    __syncthreads();
    sa = red[0][0] + red[0][1] + red[0][2] + red[0][3];
    sb = red[1][0] + red[1][1] + red[1][2] + red[1][3];

    const float ia = 1.0f / fmaxf(sqrtf(sa), 1e-12f);
    const float ib = 1.0f / fmaxf(sqrtf(sb), 1e-12f);

    int ra = 0, rb = 0;
    ra = __builtin_amdgcn_cvt_pk_fp8_f32(a.x * ia, a.y * ia, ra, false);
    ra = __builtin_amdgcn_cvt_pk_fp8_f32(a.z * ia, a.w * ia, ra, true);
    rb = __builtin_amdgcn_cvt_pk_fp8_f32(b.x * ib, b.y * ib, rb, false);
    rb = __builtin_amdgcn_cvt_pk_fp8_f32(b.z * ib, b.w * ib, rb, true);
    ((int*)(img_f8 + (size_t)row * DIM))[t] = ra;
    ((int*)(txt_f8 + (size_t)row * DIM))[t] = rb;

    float dp = (a.x * b.x + a.y * b.y + a.z * b.z + a.w * b.w) * ia * ib;
#pragma unroll
    for (int d = 1; d < 64; d <<= 1) dp += __shfl_xor(dp, d, 64);
    if (lane == 0) red[2][w] = dp;
    __syncthreads();
    if (t == 0) {
        diag[row] = red[2][0] + red[2][1] + red[2][2] + red[2][3];
        S[row] = 0.0f;
    }
}

// ---------------------------------------------------------------------------
// Kernel 2: 256x256-tile MX-fp8 MFMA GEMM (C = A . B^T), 8-phase structure.
//   8 waves (2M x 4N), each owns a 128x64 output panel; acc[8][4] f32x4.
//   LDS 128 KiB: 2 double-buffers x (A 32K | B 32K), rows of 128 B with the
//   R2-verified XOR chunk swizzle (chunk c of row r stored at c^(r&7); applied
//   by permuting the GLOBAL source, LDS dest stays lane-linear per
//   global_load_lds constraint).
//   Per K-tile: 4 phases {ds_read frags || stage next tile -> s_barrier ->
//   lgkmcnt(0) -> setprio(1) 8 MFMAs setprio(0) -> s_barrier}.  All staging
//   for tile k+1 issues in phases 0-1; the single vmcnt(0) sits at phase 3,
//   >2 phases after the last issue -> no per-K-step drain (the m97 stall).
//   A-fragments are reused across phase pairs (QN inner): 32 ds_read_b128
//   per wave per K-tile instead of 48.
//   Fused epilogue: rowsum of exp(sim - 1) -> atomicAdd into S[row].
// ---------------------------------------------------------------------------
__global__ __launch_bounds__(512, 2) void sim_lse_kernel(
    const uint8_t* __restrict__ A, const uint8_t* __restrict__ B,
    float* __restrict__ S)
{
    __shared__ __align__(16) uint8_t smem[2 * 2 * BM * BKF];   // 128 KiB

    const int t     = threadIdx.x;       // 0..511
    const int lane  = t & 63;
    const int w     = t >> 6;            // wave 0..7
    const int waveM = w >> 2;            // 0..1 : 128 rows each
    const int waveN = w & 3;             // 0..3 : 64 cols each
    const int lr    = lane & 15;         // row-in-16-tile
    const int q     = lane >> 4;         // k-quarter (f8f6f4 frag layout)
    const int swz   = lr & 7;            // read-side XOR swizzle key

    const int rowA0 = blockIdx.y * BM;
    const int rowB0 = blockIdx.x * BN;
    const uint8_t* Ablk = A + (size_t)rowA0 * DIM;
    const uint8_t* Bblk = B + (size_t)rowB0 * DIM;

    // per-lane LDS byte-offset components (chunk LSB lives in bit 4 -> ^16)
    const uint32_t lo_off = (uint32_t)(((2 * q) ^ swz) * 16);
    const uint32_t a_ro   = (uint32_t)((waveM * 128 + lr) * 128);
    const uint32_t b_ro   = (uint32_t)(32768 + (waveN * 64 + lr) * 128);

    f32x4 acc[8][4] = {};

    auto stage_half = [&](const uint8_t* gpanel, uint32_t ldsbase) {
#pragma unroll
        for (int rnd = 0; rnd < 2; ++rnd) {
            const int c   = rnd * 512 + t;        // 16B chunk id, 0..1023
            const int row = c >> 3;               // 0..127 (128 B rows)
            const int col = (c & 7) ^ (row & 7);  // pre-swizzled source chunk
            __builtin_amdgcn_global_load_lds(
                (const __attribute__((address_space(1))) void*)
                    (gpanel + (size_t)row * DIM + col * 16),
                (__attribute__((address_space(3))) void*)
                    &smem[ldsbase + (uint32_t)c * 16],
                16, 0, 0);
        }
    };

    // ---- prologue: stage K-tile 0 into buffer 0, full drain once ----------
    stage_half(Ablk,             0u);
    stage_half(Ablk + 128 * DIM, 16384u);
    stage_half(Bblk,             32768u);
    stage_half(Bblk + 128 * DIM, 49152u);
    asm volatile("s_waitcnt vmcnt(0)" ::: "memory");
    __builtin_amdgcn_s_barrier();

    // ---- main loop: 8 K-tiles x 4 phases ----------------------------------
#pragma unroll
    for (int kt = 0; kt < NT; ++kt) {
        const uint32_t abase = (uint32_t)((kt & 1) << 16);   // current buffer
        const uint32_t nbase = abase ^ 65536u;               // next buffer
        const int      k0n   = (kt + 1) * BKF;
        i32x8 af[4];                       // A frags persist across QN pair
#pragma unroll
        for (int p = 0; p < 4; ++p) {
            const int QM = p >> 1;         // 0,0,1,1
            const int QN = p & 1;          // 0,1,0,1
            if (QN == 0) {                 // fresh A quadrant (8 ds_read_b128)
#pragma unroll
                for (int m2 = 0; m2 < 4; ++m2) {
                    const uint32_t o = abase + a_ro
                                     + (uint32_t)((QM * 4 + m2) * 2048) + lo_off;
                    const i32x4 lo = *(const i32x4*)&smem[o];
                    const i32x4 hi = *(const i32x4*)&smem[o ^ 16u];
                    af[m2] = (i32x8){lo.x, lo.y, lo.z, lo.w,
                                     hi.x, hi.y, hi.z, hi.w};
                }
            }
            i32x8 bf[2];                   // B pair (4 ds_read_b128)
#pragma unroll
            for (int n2 = 0; n2 < 2; ++n2) {
                const uint32_t o = abase + b_ro
                                 + (uint32_t)((QN * 2 + n2) * 2048) + lo_off;
                const i32x4 lo = *(const i32x4*)&smem[o];
                const i32x4 hi = *(const i32x4*)&smem[o ^ 16u];
                bf[n2] = (i32x8){lo.x, lo.y, lo.z, lo.w,
                                 hi.x, hi.y, hi.z, hi.w};
            }
            // stage next tile early: A halves at p0, B halves at p1
            if (kt < NT - 1) {
                if (p == 0) {
                    stage_half(Ablk + k0n,             nbase);
                    stage_half(Ablk + 128 * DIM + k0n, nbase + 16384u);
                } else if (p == 1) {
                    stage_half(Bblk + k0n,             nbase + 32768u);
                    stage_half(Bblk + 128 * DIM + k0n, nbase + 49152u);
                }
            }
            __builtin_amdgcn_s_barrier();
            asm volatile("s_waitcnt lgkmcnt(0)" ::: "memory");
            __builtin_amdgcn_sched_barrier(0);   // keep MFMAs below the wait
            __builtin_amdgcn_s_setprio(1);
#pragma unroll
            for (int m2 = 0; m2 < 4; ++m2)
#pragma unroll
                for (int n2 = 0; n2 < 2; ++n2)
                    acc[QM * 4 + m2][QN * 2 + n2] =
                        __builtin_amdgcn_mfma_scale_f32_16x16x128_f8f6f4(
                            af[m2], bf[n2], acc[QM * 4 + m2][QN * 2 + n2],
                            0 /*fmtA=fp8*/, 0 /*fmtB=fp8*/,
                            0, 127 /*scaleA=1.0*/, 0, 127 /*scaleB=1.0*/);
            __builtin_amdgcn_s_setprio(0);
            // single per-tile drain, issued >=2 phases after last stage: free
            if (p == 3) asm volatile("s_waitcnt vmcnt(0)" ::: "memory");
            __builtin_amdgcn_s_barrier();
        }
    }

    // ---- epilogue: exp(s-1), rowsum over this block's 256 cols, atomic ----
    // C/D layout (shape-determined): col = lane&15, row = (lane>>4)*4 + reg
    const float L2E = 1.44269504088896f;
    const int rowbase = rowA0 + waveM * 128;
#pragma unroll
    for (int mi = 0; mi < 8; ++mi) {
        float s0 = 0.f, s1 = 0.f, s2 = 0.f, s3 = 0.f;
#pragma unroll
        for (int ni = 0; ni < 4; ++ni) {
            s0 += exp2f(acc[mi][ni].x * L2E - L2E);
            s1 += exp2f(acc[mi][ni].y * L2E - L2E);
            s2 += exp2f(acc[mi][ni].z * L2E - L2E);
            s3 += exp2f(acc[mi][ni].w * L2E - L2E);
        }
#pragma unroll
        for (int d = 1; d < 16; d <<= 1) {
            s0 += __shfl_xor(s0, d, 64);
            s1 += __shfl_xor(s1, d, 64);
            s2 += __shfl_xor(s2, d, 64);
            s3 += __shfl_xor(s3, d, 64);
        }
        if ((lane & 15) == 0) {
            float* dst = &S[rowbase + mi * 16 + (lane >> 4) * 4];
            atomicAdd(dst + 0, s0);
            atomicAdd(dst + 1, s1);
            atomicAdd(dst + 2, s2);
            atomicAdd(dst + 3, s3);
        }
    }
}

// ---------------------------------------------------------------------------
// Kernel 3: out = mean(log(S_i) - diag_i)   UNCHANGED
// ---------------------------------------------------------------------------
__global__ __launch_bounds__(1024) void fin_kernel(
    const float* __restrict__ S, const float* __restrict__ diag,
    float* __restrict__ out)
{
    const int t = threadIdx.x;
    float s = 0.f;
    for (int i = t; i < N_ROWS; i += 1024) s += logf(S[i]) - diag[i];
#pragma unroll
    for (int d = 1; d < 64; d <<= 1) s += __shfl_xor(s, d, 64);
    __shared__ float red[16];
    if ((t & 63) == 0) red[t >> 6] = s;
    __syncthreads();
    if (t == 0) {
        float tot = 0.f;
#pragma unroll
        for (int i = 0; i < 16; ++i) tot += red[i];
        out[0] = tot * (1.0f / N_ROWS);
    }
}

// ---------------------------------------------------------------------------
extern "C" void kernel_launch(void* const* d_in, const int* in_sizes, int n_in,
                              void* d_out, int out_size, void* d_ws, size_t ws_size,
                              hipStream_t stream)
{
    const float* img = (const float*)d_in[0];
    const float* txt = (const float*)d_in[1];
    float* out = (float*)d_out;

    char* ws = (char*)d_ws;
    uint8_t* img_f8 = (uint8_t*)ws;                                  // 8 MiB
    uint8_t* txt_f8 = (uint8_t*)(ws + (size_t)N_ROWS * DIM);         // 8 MiB
    float*   S      = (float*)(ws + (size_t)N_ROWS * DIM * 2);       // 32 KiB
    float*   diag   = S + N_ROWS;                                    // 32 KiB

    nrm_kernel<<<N_ROWS, 256, 0, stream>>>(img, txt, img_f8, txt_f8, diag, S);
    dim3 grid(N_ROWS / BN, N_ROWS / BM);
    sim_lse_kernel<<<grid, 512, 0, stream>>>(img_f8, txt_f8, S);
    fin_kernel<<<1, 1024, 0, stream>>>(S, diag, out);
}

// Round 2
// 230.704 us; speedup vs baseline: 2.0284x; 2.0284x over previous
//
#include <hip/hip_runtime.h>
#include <hip/hip_bf16.h>
#include <stdint.h>

#define N_ROWS 8192
#define DIM    1024
#define BM 256
#define BN 256
#define BKF 128          // fp8 bytes of K per tile (= one MFMA K)
#define NT (DIM / BKF)   // 8 K-tiles

typedef float   f32x4  __attribute__((ext_vector_type(4)));
typedef int     i32x4  __attribute__((ext_vector_type(4)));
typedef int     i32x8  __attribute__((ext_vector_type(8)));

// ---------------------------------------------------------------------------
// Kernel 1: fused L2-normalize (fp32 -> fp8 e4m3) + exact fp32 per-row
// diagonal + S zero-init (folds the memset dispatch).  UNCHANGED.
// ---------------------------------------------------------------------------
__global__ __launch_bounds__(256) void nrm_kernel(
    const float* __restrict__ img, const float* __restrict__ txt,
    uint8_t* __restrict__ img_f8, uint8_t* __restrict__ txt_f8,
    float* __restrict__ diag, float* __restrict__ S)
{
    const int row  = blockIdx.x;
    const int t    = threadIdx.x;
    const int lane = t & 63;
    const int w    = t >> 6;

    const float4 a = ((const float4*)(img + (size_t)row * DIM))[t];
    const float4 b = ((const float4*)(txt + (size_t)row * DIM))[t];

    float sa = a.x * a.x + a.y * a.y + a.z * a.z + a.w * a.w;
    float sb = b.x * b.x + b.y * b.y + b.z * b.z + b.w * b.w;
#pragma unroll
    for (int d = 1; d < 64; d <<= 1) {
        sa += __shfl_xor(sa, d, 64);
        sb += __shfl_xor(sb, d, 64);
    }
    __shared__ float red[3][4];
    if (lane == 0) { red[0][w] = sa; red[1][w] = sb; }
    __syncthreads();
    sa = red[0][0] + red[0][1] + red[0][2] + red[0][3];
    sb = red[1][0] + red[1][1] + red[1][2] + red[1][3];

    const float ia = 1.0f / fmaxf(sqrtf(sa), 1e-12f);
    const float ib = 1.0f / fmaxf(sqrtf(sb), 1e-12f);

    int ra = 0, rb = 0;
    ra = __builtin_amdgcn_cvt_pk_fp8_f32(a.x * ia, a.y * ia, ra, false);
    ra = __builtin_amdgcn_cvt_pk_fp8_f32(a.z * ia, a.w * ia, ra, true);
    rb = __builtin_amdgcn_cvt_pk_fp8_f32(b.x * ib, b.y * ib, rb, false);
    rb = __builtin_amdgcn_cvt_pk_fp8_f32(b.z * ib, b.w * ib, rb, true);
    ((int*)(img_f8 + (size_t)row * DIM))[t] = ra;
    ((int*)(txt_f8 + (size_t)row * DIM))[t] = rb;

    float dp = (a.x * b.x + a.y * b.y + a.z * b.z + a.w * b.w) * ia * ib;
#pragma unroll
    for (int d = 1; d < 64; d <<= 1) dp += __shfl_xor(dp, d, 64);
    if (lane == 0) red[2][w] = dp;
    __syncthreads();
    if (t == 0) {
        diag[row] = red[2][0] + red[2][1] + red[2][2] + red[2][3];
        S[row] = 0.0f;
    }
}

// ---------------------------------------------------------------------------
// Kernel 2: 256x256-tile MX-fp8 MFMA GEMM (C = A . B^T), 8-phase structure.
//   8 waves (2M x 4N), each owns a 128x64 output panel; acc[8][4] f32x4.
//   LDS 128 KiB => occupancy is 1 block/CU (2 waves/SIMD) no matter what, so
//   __launch_bounds__(512) ONLY: R1's (512,2) made the compiler target a
//   128-VGPR budget (4 waves/SIMD it could never get) and spilled the whole
//   accumulator to scratch (700 MB WRITE_SIZE, MfmaUtil 7.7%).
//   kt loop NOT unrolled (smaller scheduling scope / live ranges); phase loop
//   unrolled so all acc/frag indices stay compile-time (no scratch, rule #20).
//   Per K-tile: 4 phases {ds_read frags || stage next tile -> s_barrier ->
//   lgkmcnt(0) -> setprio(1) 8 MFMAs setprio(0) -> s_barrier}.  All staging
//   for tile k+1 issues in phases 0-1; single vmcnt(0) at phase 3.
//   Fused epilogue: rowsum of exp(sim - 1) -> atomicAdd into S[row].
// ---------------------------------------------------------------------------
__global__ __launch_bounds__(512) void sim_lse_kernel(
    const uint8_t* __restrict__ A, const uint8_t* __restrict__ B,
    float* __restrict__ S)
{
    __shared__ __align__(16) uint8_t smem[2 * 2 * BM * BKF];   // 128 KiB

    const int t     = threadIdx.x;       // 0..511
    const int lane  = t & 63;
    const int w     = t >> 6;            // wave 0..7
    const int waveM = w >> 2;            // 0..1 : 128 rows each
    const int waveN = w & 3;             // 0..3 : 64 cols each
    const int lr    = lane & 15;         // row-in-16-tile
    const int q     = lane >> 4;         // k-quarter (f8f6f4 frag layout)
    const int swz   = lr & 7;            // read-side XOR swizzle key

    const int rowA0 = blockIdx.y * BM;
    const int rowB0 = blockIdx.x * BN;
    const uint8_t* Ablk = A + (size_t)rowA0 * DIM;
    const uint8_t* Bblk = B + (size_t)rowB0 * DIM;

    // per-lane LDS byte-offset components (chunk LSB lives in bit 4 -> ^16)
    const uint32_t lo_off = (uint32_t)(((2 * q) ^ swz) * 16);
    const uint32_t a_ro   = (uint32_t)((waveM * 128 + lr) * 128);
    const uint32_t b_ro   = (uint32_t)(32768 + (waveN * 64 + lr) * 128);

    f32x4 acc[8][4] = {};

    auto stage_half = [&](const uint8_t* gpanel, uint32_t ldsbase) {
#pragma unroll
        for (int rnd = 0; rnd < 2; ++rnd) {
            const int c   = rnd * 512 + t;        // 16B chunk id, 0..1023
            const int row = c >> 3;               // 0..127 (128 B rows)
            const int col = (c & 7) ^ (row & 7);  // pre-swizzled source chunk
            __builtin_amdgcn_global_load_lds(
                (const __attribute__((address_space(1))) void*)
                    (gpanel + (size_t)row * DIM + col * 16),
                (__attribute__((address_space(3))) void*)
                    &smem[ldsbase + (uint32_t)c * 16],
                16, 0, 0);
        }
    };

    // ---- prologue: stage K-tile 0 into buffer 0, full drain once ----------
    stage_half(Ablk,             0u);
    stage_half(Ablk + 128 * DIM, 16384u);
    stage_half(Bblk,             32768u);
    stage_half(Bblk + 128 * DIM, 49152u);
    asm volatile("s_waitcnt vmcnt(0)" ::: "memory");
    __builtin_amdgcn_s_barrier();

    // ---- main loop: 8 K-tiles x 4 phases ----------------------------------
#pragma unroll 1
    for (int kt = 0; kt < NT; ++kt) {
        const uint32_t abase = (uint32_t)((kt & 1) << 16);   // current buffer
        const uint32_t nbase = abase ^ 65536u;               // next buffer
        const int      k0n   = (kt + 1) * BKF;
        i32x8 af[4];                       // A frags persist across QN pair
#pragma unroll
        for (int p = 0; p < 4; ++p) {
            const int QM = p >> 1;         // 0,0,1,1
            const int QN = p & 1;          // 0,1,0,1
            if (QN == 0) {                 // fresh A quadrant (8 ds_read_b128)
#pragma unroll
                for (int m2 = 0; m2 < 4; ++m2) {
                    const uint32_t o = abase + a_ro
                                     + (uint32_t)((QM * 4 + m2) * 2048) + lo_off;
                    const i32x4 lo = *(const i32x4*)&smem[o];
                    const i32x4 hi = *(const i32x4*)&smem[o ^ 16u];
                    af[m2] = (i32x8){lo.x, lo.y, lo.z, lo.w,
                                     hi.x, hi.y, hi.z, hi.w};
                }
            }
            i32x8 bf[2];                   // B pair (4 ds_read_b128)
#pragma unroll
            for (int n2 = 0; n2 < 2; ++n2) {
                const uint32_t o = abase + b_ro
                                 + (uint32_t)((QN * 2 + n2) * 2048) + lo_off;
                const i32x4 lo = *(const i32x4*)&smem[o];
                const i32x4 hi = *(const i32x4*)&smem[o ^ 16u];
                bf[n2] = (i32x8){lo.x, lo.y, lo.z, lo.w,
                                 hi.x, hi.y, hi.z, hi.w};
            }
            // stage next tile early: A halves at p0, B halves at p1
            if (kt < NT - 1) {
                if (p == 0) {
                    stage_half(Ablk + k0n,             nbase);
                    stage_half(Ablk + 128 * DIM + k0n, nbase + 16384u);
                } else if (p == 1) {
                    stage_half(Bblk + k0n,             nbase + 32768u);
                    stage_half(Bblk + 128 * DIM + k0n, nbase + 49152u);
                }
            }
            __builtin_amdgcn_s_barrier();
            asm volatile("s_waitcnt lgkmcnt(0)" ::: "memory");
            __builtin_amdgcn_sched_barrier(0);   // keep MFMAs below the wait
            __builtin_amdgcn_s_setprio(1);
#pragma unroll
            for (int m2 = 0; m2 < 4; ++m2)
#pragma unroll
                for (int n2 = 0; n2 < 2; ++n2)
                    acc[QM * 4 + m2][QN * 2 + n2] =
                        __builtin_amdgcn_mfma_scale_f32_16x16x128_f8f6f4(
                            af[m2], bf[n2], acc[QM * 4 + m2][QN * 2 + n2],
                            0 /*fmtA=fp8*/, 0 /*fmtB=fp8*/,
                            0, 127 /*scaleA=1.0*/, 0, 127 /*scaleB=1.0*/);
            __builtin_amdgcn_s_setprio(0);
            // single per-tile drain, issued >=2 phases after last stage: free
            if (p == 3) asm volatile("s_waitcnt vmcnt(0)" ::: "memory");
            __builtin_amdgcn_s_barrier();
        }
    }

    // ---- epilogue: exp(s-1), rowsum over this block's 256 cols, atomic ----
    // C/D layout (shape-determined): col = lane&15, row = (lane>>4)*4 + reg
    const float L2E = 1.44269504088896f;
    const int rowbase = rowA0 + waveM * 128;
#pragma unroll
    for (int mi = 0; mi < 8; ++mi) {
        float s0 = 0.f, s1 = 0.f, s2 = 0.f, s3 = 0.f;
#pragma unroll
        for (int ni = 0; ni < 4; ++ni) {
            s0 += exp2f(acc[mi][ni].x * L2E - L2E);
            s1 += exp2f(acc[mi][ni].y * L2E - L2E);
            s2 += exp2f(acc[mi][ni].z * L2E - L2E);
            s3 += exp2f(acc[mi][ni].w * L2E - L2E);
        }
#pragma unroll
        for (int d = 1; d < 16; d <<= 1) {
            s0 += __shfl_xor(s0, d, 64);
            s1 += __shfl_xor(s1, d, 64);
            s2 += __shfl_xor(s2, d, 64);
            s3 += __shfl_xor(s3, d, 64);
        }
        if ((lane & 15) == 0) {
            float* dst = &S[rowbase + mi * 16 + (lane >> 4) * 4];
            atomicAdd(dst + 0, s0);
            atomicAdd(dst + 1, s1);
            atomicAdd(dst + 2, s2);
            atomicAdd(dst + 3, s3);
        }
    }
}

// ---------------------------------------------------------------------------
// Kernel 3: out = mean(log(S_i) - diag_i)   UNCHANGED
// ---------------------------------------------------------------------------
__global__ __launch_bounds__(1024) void fin_kernel(
    const float* __restrict__ S, const float* __restrict__ diag,
    float* __restrict__ out)
{
    const int t = threadIdx.x;
    float s = 0.f;
    for (int i = t; i < N_ROWS; i += 1024) s += logf(S[i]) - diag[i];
#pragma unroll
    for (int d = 1; d < 64; d <<= 1) s += __shfl_xor(s, d, 64);
    __shared__ float red[16];
    if ((t & 63) == 0) red[t >> 6] = s;
    __syncthreads();
    if (t == 0) {
        float tot = 0.f;
#pragma unroll
        for (int i = 0; i < 16; ++i) tot += red[i];
        out[0] = tot * (1.0f / N_ROWS);
    }
}

// ---------------------------------------------------------------------------
extern "C" void kernel_launch(void* const* d_in, const int* in_sizes, int n_in,
                              void* d_out, int out_size, void* d_ws, size_t ws_size,
                              hipStream_t stream)
{
    const float* img = (const float*)d_in[0];
    const float* txt = (const float*)d_in[1];
    float* out = (float*)d_out;

    char* ws = (char*)d_ws;
    uint8_t* img_f8 = (uint8_t*)ws;                                  // 8 MiB
    uint8_t* txt_f8 = (uint8_t*)(ws + (size_t)N_ROWS * DIM);         // 8 MiB
    float*   S      = (float*)(ws + (size_t)N_ROWS * DIM * 2);       // 32 KiB
    float*   diag   = S + N_ROWS;                                    // 32 KiB

    nrm_kernel<<<N_ROWS, 256, 0, stream>>>(img, txt, img_f8, txt_f8, diag, S);
    dim3 grid(N_ROWS / BN, N_ROWS / BM);
    sim_lse_kernel<<<grid, 512, 0, stream>>>(img_f8, txt_f8, S);
    fin_kernel<<<1, 1024, 0, stream>>>(S, diag, out);
}